// Round 1
// baseline (366.499 us; speedup 1.0000x reference)
//
#include <hip/hip_runtime.h>
#include <cstdint>

typedef unsigned short u16;
typedef __attribute__((ext_vector_type(8))) short bf16x8;
typedef __attribute__((ext_vector_type(4))) float f32x4;

#define NB 4
#define NT 2048
#define NC 1024
#define NH 16
#define ND 64
#define NM (NB*NT)      // 8192
#define N3C (3*NC)      // 3072

static __device__ __forceinline__ u16 f2bf(float f){
  union { float f; uint32_t u; } v; v.f = f;
  return (u16)((v.u + 0x7fffu + ((v.u >> 16) & 1u)) >> 16);
}

// async 16B global->LDS (CK-style address-space casts; LDS dest is wave-uniform base + lane*16)
static __device__ __forceinline__ void gld_lds16(void* lds, const void* g){
  auto lp = reinterpret_cast<__attribute__((address_space(3))) uint32_t*>(
      reinterpret_cast<uintptr_t>(lds));
  auto gp = reinterpret_cast<__attribute__((address_space(1))) uint32_t*>(
      reinterpret_cast<uintptr_t>(g));
  __builtin_amdgcn_global_load_lds(gp, lp, 16, 0, 0);
}

// ---------------- elementwise cast fp32 -> bf16 ----------------
__global__ __launch_bounds__(256) void k_cast(const float* __restrict__ in,
                                              u16* __restrict__ out){
  const int i = (blockIdx.x * 256 + threadIdx.x) * 4;
  const float4 vv = *reinterpret_cast<const float4*>(in + i);
  union { u16 s[4]; uint64_t u; } pk;
  pk.s[0] = f2bf(vv.x); pk.s[1] = f2bf(vv.y);
  pk.s[2] = f2bf(vv.z); pk.s[3] = f2bf(vv.w);
  *reinterpret_cast<uint64_t*>(out + i) = pk.u;
}

// ---------------- tiled transpose + cast: in[R][Cc] fp32 -> out[Cc][R] bf16 ----------------
__global__ __launch_bounds__(256) void k_transpose_cast(const float* __restrict__ in,
                                                        u16* __restrict__ out,
                                                        int R, int Cc){
  __shared__ float tile[32][33];
  const int bx = blockIdx.x * 32, by = blockIdx.y * 32;
  const int tx = threadIdx.x, ty = threadIdx.y;
#pragma unroll
  for (int i = 0; i < 32; i += 8)
    tile[ty + i][tx] = in[(size_t)(by + ty + i) * Cc + bx + tx];
  __syncthreads();
#pragma unroll
  for (int i = 0; i < 32; i += 8)
    out[(size_t)(bx + ty + i) * R + by + tx] = f2bf(tile[tx][ty + i]);
}

// ---------------- shared GEMM main loop: C[128x128] tile, A[M][K] * Bt[N][K]^T ----------------
static __device__ __forceinline__ void gemm_mainloop(
    const u16* __restrict__ A, const u16* __restrict__ Bt, int K,
    int m0, int n0, u16* As, u16* Bs, f32x4 acc[4][4])
{
  const int tid = threadIdx.x;
  const int wave = tid >> 6, lane = tid & 63;
  const int wm = wave >> 1, wn = wave & 1;
  const int o0 = tid * 8, o1 = o0 + 2048;           // elem offsets in the 128x32 tile
  const u16* Ag0 = A  + (size_t)(m0 + (o0 >> 5)) * K + (o0 & 31);
  const u16* Ag1 = A  + (size_t)(m0 + (o1 >> 5)) * K + (o1 & 31);
  const u16* Bg0 = Bt + (size_t)(n0 + (o0 >> 5)) * K + (o0 & 31);
  const u16* Bg1 = Bt + (size_t)(n0 + (o1 >> 5)) * K + (o1 & 31);
  u16* AsW = As + wave * 512;   // wave-uniform LDS base (1024 B per wave)
  u16* BsW = Bs + wave * 512;
  const int kb = (lane >> 4) * 8, rl = lane & 15;

  for (int kt = 0; kt < K; kt += 32){
    gld_lds16(AsW,        Ag0 + kt);
    gld_lds16(AsW + 2048, Ag1 + kt);
    gld_lds16(BsW,        Bg0 + kt);
    gld_lds16(BsW + 2048, Bg1 + kt);
    __syncthreads();
    bf16x8 af[4], bfr[4];
#pragma unroll
    for (int i = 0; i < 4; i++){
      af[i]  = *reinterpret_cast<const bf16x8*>(&As[(wm * 64 + i * 16 + rl) * 32 + kb]);
      bfr[i] = *reinterpret_cast<const bf16x8*>(&Bs[(wn * 64 + i * 16 + rl) * 32 + kb]);
    }
#pragma unroll
    for (int i = 0; i < 4; i++)
#pragma unroll
      for (int j = 0; j < 4; j++)
        acc[i][j] = __builtin_amdgcn_mfma_f32_16x16x32_bf16(af[i], bfr[j], acc[i][j], 0, 0, 0);
    __syncthreads();
  }
}

// ---------------- GEMM 1: x @ w_qkv + b_qkv -> scatter into Q,K,V [B,H,T,D] bf16 ----------------
__global__ __launch_bounds__(256) void k_gemm_qkv(
    const u16* __restrict__ A, const u16* __restrict__ Bt,
    const float* __restrict__ bias,
    u16* __restrict__ qo, u16* __restrict__ ko, u16* __restrict__ vo)
{
  __shared__ u16 As[128 * 32], Bs[128 * 32];
  f32x4 acc[4][4] = {};
  const int m0 = blockIdx.y * 128, n0 = blockIdx.x * 128;
  gemm_mainloop(A, Bt, NC, m0, n0, As, Bs, acc);

  const int tid = threadIdx.x;
  const int wave = tid >> 6, lane = tid & 63;
  const int wm = wave >> 1, wn = wave & 1;
  const int rl = lane & 15, rg = lane >> 4;
#pragma unroll
  for (int j = 0; j < 4; j++){
    const int n = n0 + wn * 64 + j * 16 + rl;
    const int which = n >> 10;
    const int c = n & 1023;
    const int h = c >> 6, d = c & 63;
    u16* dst = (which == 0) ? qo : ((which == 1) ? ko : vo);
    const float bb = bias[n];
    const float sc = (which == 0) ? 0.125f : 1.0f;   // fold 1/sqrt(D) into Q (exact)
#pragma unroll
    for (int i = 0; i < 4; i++){
#pragma unroll
      for (int r = 0; r < 4; r++){
        const int m = m0 + wm * 64 + i * 16 + rg * 4 + r;
        const int b = m >> 11, t = m & 2047;
        dst[(((size_t)(b * NH + h)) * NT + t) * ND + d] = f2bf((acc[i][j][r] + bb) * sc);
      }
    }
  }
}

// ---------------- GEMM 2: attn_out @ w_proj + b_proj -> fp32 out ----------------
__global__ __launch_bounds__(256) void k_gemm_proj(
    const u16* __restrict__ A, const u16* __restrict__ Bt,
    const float* __restrict__ bias, float* __restrict__ out)
{
  __shared__ u16 As[128 * 32], Bs[128 * 32];
  f32x4 acc[4][4] = {};
  const int m0 = blockIdx.y * 128, n0 = blockIdx.x * 128;
  gemm_mainloop(A, Bt, NC, m0, n0, As, Bs, acc);

  const int tid = threadIdx.x;
  const int wave = tid >> 6, lane = tid & 63;
  const int wm = wave >> 1, wn = wave & 1;
  const int rl = lane & 15, rg = lane >> 4;
#pragma unroll
  for (int i = 0; i < 4; i++){
#pragma unroll
    for (int r = 0; r < 4; r++){
      const int m = m0 + wm * 64 + i * 16 + rg * 4 + r;
#pragma unroll
      for (int j = 0; j < 4; j++){
        const int n = n0 + wn * 64 + j * 16 + rl;
        out[(size_t)m * NC + n] = acc[i][j][r] + bias[n];
      }
    }
  }
}

// ---------------- causal flash attention: 64 q-rows / block (16 per wave), KV tiles of 64 ----------------
__global__ __launch_bounds__(256) void k_flash(
    const u16* __restrict__ q, const u16* __restrict__ k,
    const u16* __restrict__ v, u16* __restrict__ ao)
{
  __shared__ u16 Ks[64 * 64];       // row kj, elem-swizzled: e ^= (kj&7)<<3
  __shared__ u16 Vt[64 * 72];       // [d][kj], padded rows (144B, 16B-aligned frags)
  __shared__ u16 Ps[4][16 * 72];    // per-wave P tile
  const int tid = threadIdx.x, wave = tid >> 6, lane = tid & 63;
  const int rl = lane & 15, rg = lane >> 4;
  const int qt = blockIdx.x, bh = blockIdx.y;
  const size_t base = (size_t)bh * NT * ND;
  const u16* Qg = q + base + (size_t)qt * 64 * ND;
  const u16* Kg = k + base;
  const u16* Vg = v + base;

  // Q fragments held in registers for the whole kernel (A-frag: row=lane&15, k=(lane>>4)*8..+7)
  bf16x8 qf[2];
  {
    const u16* qrow = Qg + (wave * 16 + rl) * ND;
    qf[0] = *reinterpret_cast<const bf16x8*>(qrow + rg * 8);
    qf[1] = *reinterpret_cast<const bf16x8*>(qrow + 32 + rg * 8);
  }

  f32x4 o[4] = {};
  float mrun[4] = {-1e30f, -1e30f, -1e30f, -1e30f};
  float lrun[4] = {0.f, 0.f, 0.f, 0.f};

  for (int kt = 0; kt <= qt; ++kt){
    __syncthreads();   // previous iteration's LDS reads done
    // ---- stage K (swizzled) and V^T (transposed, staggered writes) ----
#pragma unroll
    for (int it = 0; it < 2; ++it){
      const int cc = it * 256 + tid;
      const int kj = cc >> 3, d0 = (cc & 7) * 8;
      const bf16x8 kvv = *reinterpret_cast<const bf16x8*>(Kg + (size_t)(kt * 64 + kj) * ND + d0);
      *reinterpret_cast<bf16x8*>(&Ks[kj * 64 + (d0 ^ ((kj & 7) << 3))]) = kvv;
      const bf16x8 vvv = *reinterpret_cast<const bf16x8*>(Vg + (size_t)(kt * 64 + kj) * ND + d0);
#pragma unroll
      for (int j = 0; j < 8; j++){
        const int jj = (j + (tid & 7)) & 7;    // stagger to spread banks
        Vt[(d0 + jj) * 72 + kj] = (u16)vvv[jj];
      }
    }
    __syncthreads();

    // ---- S = Q K^T  (B-frag: col=kj=lane&15, rows d=(lane>>4)*8..+7) ----
    f32x4 s[4];
#pragma unroll
    for (int nf = 0; nf < 4; nf++){
      const int kj = nf * 16 + rl;
      const u16* krow = &Ks[kj * 64];
      const bf16x8 kf0 = *reinterpret_cast<const bf16x8*>(&krow[(rg * 8) ^ ((kj & 7) << 3)]);
      const bf16x8 kf1 = *reinterpret_cast<const bf16x8*>(&krow[(32 + rg * 8) ^ ((kj & 7) << 3)]);
      f32x4 a = {};
      a = __builtin_amdgcn_mfma_f32_16x16x32_bf16(qf[0], kf0, a, 0, 0, 0);
      a = __builtin_amdgcn_mfma_f32_16x16x32_bf16(qf[1], kf1, a, 0, 0, 0);
      s[nf] = a;
    }

    // ---- causal mask (only diagonal tile is partial: QB==KB==64, tiles aligned) ----
    if (kt == qt){
#pragma unroll
      for (int nf = 0; nf < 4; nf++){
        const int kl = nf * 16 + rl;
#pragma unroll
        for (int r = 0; r < 4; r++){
          const int ql = wave * 16 + rg * 4 + r;
          if (kl > ql) s[nf][r] = -1e30f;
        }
      }
    }

    // ---- online softmax: row qi lives in 16 lanes (same lane>>4 group), reg r ----
#pragma unroll
    for (int r = 0; r < 4; r++){
      float rowmax = fmaxf(fmaxf(s[0][r], s[1][r]), fmaxf(s[2][r], s[3][r]));
      rowmax = fmaxf(rowmax, __shfl_xor(rowmax, 1));
      rowmax = fmaxf(rowmax, __shfl_xor(rowmax, 2));
      rowmax = fmaxf(rowmax, __shfl_xor(rowmax, 4));
      rowmax = fmaxf(rowmax, __shfl_xor(rowmax, 8));
      const float mnew = fmaxf(mrun[r], rowmax);
      const float alpha = __expf(mrun[r] - mnew);
      mrun[r] = mnew;
      float rs = 0.f;
#pragma unroll
      for (int nf = 0; nf < 4; nf++){
        const float p = __expf(s[nf][r] - mnew);
        s[nf][r] = p;
        rs += p;
      }
      rs += __shfl_xor(rs, 1);
      rs += __shfl_xor(rs, 2);
      rs += __shfl_xor(rs, 4);
      rs += __shfl_xor(rs, 8);
      lrun[r] = lrun[r] * alpha + rs;
#pragma unroll
      for (int fo = 0; fo < 4; fo++) o[fo][r] *= alpha;
    }

    // ---- P (C-frag layout) -> per-wave LDS -> A-frag layout; then PV ----
    u16* Pw = &Ps[wave][0];
#pragma unroll
    for (int nf = 0; nf < 4; nf++){
      const int kj = nf * 16 + rl;
#pragma unroll
      for (int r = 0; r < 4; r++)
        Pw[(rg * 4 + r) * 72 + kj] = f2bf(s[nf][r]);
    }
#pragma unroll
    for (int half = 0; half < 2; ++half){
      const bf16x8 pf = *reinterpret_cast<const bf16x8*>(&Pw[rl * 72 + half * 32 + rg * 8]);
#pragma unroll
      for (int fo = 0; fo < 4; fo++){
        const bf16x8 vf = *reinterpret_cast<const bf16x8*>(&Vt[(fo * 16 + rl) * 72 + half * 32 + rg * 8]);
        o[fo] = __builtin_amdgcn_mfma_f32_16x16x32_bf16(pf, vf, o[fo], 0, 0, 0);
      }
    }
  }

  // ---- epilogue: O/l -> attn_out [B,T,C] bf16 ----
  const int b = bh >> 4, h = bh & 15;
#pragma unroll
  for (int fo = 0; fo < 4; fo++){
#pragma unroll
    for (int r = 0; r < 4; r++){
      const int t = qt * 64 + wave * 16 + rg * 4 + r;
      const int c = h * 64 + fo * 16 + rl;
      ao[((size_t)b * NT + t) * NC + c] = f2bf(o[fo][r] / lrun[r]);
    }
  }
}

extern "C" void kernel_launch(void* const* d_in, const int* in_sizes, int n_in,
                              void* d_out, int out_size, void* d_ws, size_t ws_size,
                              hipStream_t stream){
  const float* x      = (const float*)d_in[0];
  const float* w_qkv  = (const float*)d_in[1];
  const float* b_qkv  = (const float*)d_in[2];
  const float* w_proj = (const float*)d_in[3];
  const float* b_proj = (const float*)d_in[4];
  float* out = (float*)d_out;

  u16* ws = (u16*)d_ws;
  u16* xb     = ws;                 //  8388608 elems  [B,T,C] bf16
  u16* qb     = ws + 8388608;       //  [B,H,T,D]
  u16* kb     = ws + 16777216;      //  [B,H,T,D]
  u16* vb     = ws + 25165824;      //  [B,H,T,D]
  u16* aob    = ws + 33554432;      //  [B,T,C]
  u16* wqkvT  = ws + 41943040;      //  [3C,C]
  u16* wprojT = ws + 45088768;      //  [C,C]

  k_cast<<<8388608 / 1024, 256, 0, stream>>>(x, xb);
  k_transpose_cast<<<dim3(N3C / 32, NC / 32), dim3(32, 8), 0, stream>>>(w_qkv, wqkvT, NC, N3C);
  k_transpose_cast<<<dim3(NC / 32, NC / 32), dim3(32, 8), 0, stream>>>(w_proj, wprojT, NC, NC);
  k_gemm_qkv<<<dim3(N3C / 128, NM / 128), 256, 0, stream>>>(xb, wqkvT, b_qkv, qb, kb, vb);
  k_flash<<<dim3(NT / 64, NB * NH), 256, 0, stream>>>(qb, kb, vb, aob);
  k_gemm_proj<<<dim3(NC / 128, NM / 128), 256, 0, stream>>>(aob, wprojT, b_proj, out);
}

// Round 4
// 293.110 us; speedup vs baseline: 1.2504x; 1.2504x over previous
//
#include <hip/hip_runtime.h>
#include <cstdint>

typedef unsigned short u16;
typedef uint32_t u32;
typedef __attribute__((ext_vector_type(8))) short bf16x8;
typedef __attribute__((ext_vector_type(4))) short bf16x4;
typedef __attribute__((ext_vector_type(4))) float f32x4;

#define NB 4
#define NT 2048
#define NC 1024
#define NH 16
#define ND 64
#define NM (NB*NT)      // 8192
#define N3C (3*NC)      // 3072

// Q scale: 1/sqrt(64) * log2(e)  (softmax runs in log2 domain -> exp2)
#define QSCALE 0.18033688011112042f

static __device__ __forceinline__ u16 f2bf(float f){
  union { float f; uint32_t u; } v; v.f = f;
  return (u16)((v.u + 0x7fffu + ((v.u >> 16) & 1u)) >> 16);
}

// async 16B global->LDS (LDS dest is wave-uniform base + lane*16)
static __device__ __forceinline__ void gld_lds16(void* lds, const void* g){
  auto lp = reinterpret_cast<__attribute__((address_space(3))) uint32_t*>(
      reinterpret_cast<uintptr_t>(lds));
  auto gp = reinterpret_cast<__attribute__((address_space(1))) uint32_t*>(
      reinterpret_cast<uintptr_t>(g));
  __builtin_amdgcn_global_load_lds(gp, lp, 16, 0, 0);
}

static __device__ __forceinline__ f32x4 mfma16(bf16x4 a, bf16x4 b, f32x4 c){
#if __has_builtin(__builtin_amdgcn_mfma_f32_16x16x16bf16_1k)
  return __builtin_amdgcn_mfma_f32_16x16x16bf16_1k(a, b, c, 0, 0, 0);
#else
  asm("v_mfma_f32_16x16x16_bf16 %0, %1, %2, %0" : "+v"(c) : "v"(a), "v"(b));
  return c;
#endif
}

// ---------------- elementwise cast fp32 -> bf16 ----------------
__global__ __launch_bounds__(256) void k_cast(const float* __restrict__ in,
                                              u16* __restrict__ out){
  const int i = (blockIdx.x * 256 + threadIdx.x) * 4;
  const float4 vv = *reinterpret_cast<const float4*>(in + i);
  union { u16 s[4]; uint64_t u; } pk;
  pk.s[0] = f2bf(vv.x); pk.s[1] = f2bf(vv.y);
  pk.s[2] = f2bf(vv.z); pk.s[3] = f2bf(vv.w);
  *reinterpret_cast<uint64_t*>(out + i) = pk.u;
}

// ---------------- tiled transpose + cast: in[R][Cc] fp32 -> out[Cc][R] bf16 ----------------
__global__ __launch_bounds__(256) void k_transpose_cast(const float* __restrict__ in,
                                                        u16* __restrict__ out,
                                                        int R, int Cc){
  __shared__ float tile[32][33];
  const int bx = blockIdx.x * 32, by = blockIdx.y * 32;
  const int tx = threadIdx.x, ty = threadIdx.y;
#pragma unroll
  for (int i = 0; i < 32; i += 8)
    tile[ty + i][tx] = in[(size_t)(by + ty + i) * Cc + bx + tx];
  __syncthreads();
#pragma unroll
  for (int i = 0; i < 32; i += 8)
    out[(size_t)(bx + ty + i) * R + by + tx] = f2bf(tile[tx][ty + i]);
}

// ---------------- shared GEMM main loop: C[128x128] tile, A[M][K] * Bt[N][K]^T ----------------
static __device__ __forceinline__ void gemm_mainloop(
    const u16* __restrict__ A, const u16* __restrict__ Bt, int K,
    int m0, int n0, u16* As, u16* Bs, f32x4 acc[4][4])
{
  const int tid = threadIdx.x;
  const int wave = tid >> 6, lane = tid & 63;
  const int wm = wave >> 1, wn = wave & 1;
  const int o0 = tid * 8, o1 = o0 + 2048;           // elem offsets in the 128x32 tile
  const u16* Ag0 = A  + (size_t)(m0 + (o0 >> 5)) * K + (o0 & 31);
  const u16* Ag1 = A  + (size_t)(m0 + (o1 >> 5)) * K + (o1 & 31);
  const u16* Bg0 = Bt + (size_t)(n0 + (o0 >> 5)) * K + (o0 & 31);
  const u16* Bg1 = Bt + (size_t)(n0 + (o1 >> 5)) * K + (o1 & 31);
  u16* AsW = As + wave * 512;   // wave-uniform LDS base (1024 B per wave)
  u16* BsW = Bs + wave * 512;
  const int kb = (lane >> 4) * 8, rl = lane & 15;

  for (int kt = 0; kt < K; kt += 32){
    gld_lds16(AsW,        Ag0 + kt);
    gld_lds16(AsW + 2048, Ag1 + kt);
    gld_lds16(BsW,        Bg0 + kt);
    gld_lds16(BsW + 2048, Bg1 + kt);
    __syncthreads();
    bf16x8 af[4], bfr[4];
#pragma unroll
    for (int i = 0; i < 4; i++){
      af[i]  = *reinterpret_cast<const bf16x8*>(&As[(wm * 64 + i * 16 + rl) * 32 + kb]);
      bfr[i] = *reinterpret_cast<const bf16x8*>(&Bs[(wn * 64 + i * 16 + rl) * 32 + kb]);
    }
#pragma unroll
    for (int i = 0; i < 4; i++)
#pragma unroll
      for (int j = 0; j < 4; j++)
        acc[i][j] = __builtin_amdgcn_mfma_f32_16x16x32_bf16(af[i], bfr[j], acc[i][j], 0, 0, 0);
    __syncthreads();
  }
}

// ---------------- GEMM 1: x @ w_qkv + b_qkv -> Q (scaled), K (swizzled), V (transposed+swizzled) ----------------
// Q: [b,h,t,d] standard, values * QSCALE
// K: per (b,h): tile kt (4096 elems): (t&63)*64 + (d ^ ((t&7)<<3))
// V: per (b,h): tile kt (4096 elems): d*64 + (((t>>2)&15 ^ (d&7))<<2) + (t&3)   [transposed]
__global__ __launch_bounds__(256) void k_gemm_qkv(
    const u16* __restrict__ A, const u16* __restrict__ Bt,
    const float* __restrict__ bias,
    u16* __restrict__ qo, u16* __restrict__ ko, u16* __restrict__ vo)
{
  __shared__ u16 As[128 * 32], Bs[128 * 32];
  f32x4 acc[4][4] = {};
  const int m0 = blockIdx.y * 128, n0 = blockIdx.x * 128;
  gemm_mainloop(A, Bt, NC, m0, n0, As, Bs, acc);

  const int tid = threadIdx.x;
  const int wave = tid >> 6, lane = tid & 63;
  const int wm = wave >> 1, wn = wave & 1;
  const int rl = lane & 15, rg = lane >> 4;
  const int which = n0 >> 10;   // uniform per block: 0=Q 1=K 2=V
#pragma unroll
  for (int j = 0; j < 4; j++){
    const int n = n0 + wn * 64 + j * 16 + rl;
    const int cc = n & 1023;
    const int h = cc >> 6, d = cc & 63;
    const float bb = bias[n];
#pragma unroll
    for (int i = 0; i < 4; i++){
#pragma unroll
      for (int r = 0; r < 4; r++){
        const int m = m0 + wm * 64 + i * 16 + rg * 4 + r;
        const int b = m >> 11, t = m & 2047;
        const size_t bhb = ((size_t)(b * NH + h)) * NT * ND;
        const float val = acc[i][j][r] + bb;
        if (which == 0){
          qo[bhb + (size_t)t * ND + d] = f2bf(val * QSCALE);
        } else if (which == 1){
          ko[bhb + (size_t)(t >> 6) * 4096 + (t & 63) * 64 + (d ^ ((t & 7) << 3))] = f2bf(val);
        } else {
          vo[bhb + (size_t)(t >> 6) * 4096 + d * 64 + ((((t >> 2) & 15) ^ (d & 7)) << 2) + (t & 3)] = f2bf(val);
        }
      }
    }
  }
}

// ---------------- GEMM 2: attn_out @ w_proj + b_proj -> fp32 out ----------------
__global__ __launch_bounds__(256) void k_gemm_proj(
    const u16* __restrict__ A, const u16* __restrict__ Bt,
    const float* __restrict__ bias, float* __restrict__ out)
{
  __shared__ u16 As[128 * 32], Bs[128 * 32];
  f32x4 acc[4][4] = {};
  const int m0 = blockIdx.y * 128, n0 = blockIdx.x * 128;
  gemm_mainloop(A, Bt, NC, m0, n0, As, Bs, acc);

  const int tid = threadIdx.x;
  const int wave = tid >> 6, lane = tid & 63;
  const int wm = wave >> 1, wn = wave & 1;
  const int rl = lane & 15, rg = lane >> 4;
#pragma unroll
  for (int i = 0; i < 4; i++){
#pragma unroll
    for (int r = 0; r < 4; r++){
      const int m = m0 + wm * 64 + i * 16 + rg * 4 + r;
#pragma unroll
      for (int j = 0; j < 4; j++){
        const int n = n0 + wn * 64 + j * 16 + rl;
        out[(size_t)m * NC + n] = acc[i][j][r] + bias[n];
      }
    }
  }
}

// ---------------- causal flash attention (swapped-QK^T, in-register softmax) ----------------
// 64 q-rows / block (16 per wave). K-tiles of 64. K,V staged via linear global_load_lds
// from pre-swizzled global layouts; softmax lane-local (row q = lane&15).
__global__ __launch_bounds__(256) void k_flash(
    const u16* __restrict__ q, const u16* __restrict__ k,
    const u16* __restrict__ v, u16* __restrict__ ao)
{
  __shared__ u16 Ks[64 * 64];   // row kj, 16B-chunk swizzle: chunk' = chunk ^ (kj&7)
  __shared__ u16 Vt[64 * 64];   // row d, 8B-chunk swizzle: chunk8' = chunk8 ^ (d&7)
  const int tid = threadIdx.x, wave = tid >> 6, lane = tid & 63;
  const int cl = lane & 15, g = lane >> 4;
  const int qt = blockIdx.x, bh = blockIdx.y;
  const size_t base = (size_t)bh * NT * ND;

  // Q B-frag (and A-frag; same mapping): lane holds Q[q=cl][d=g*8+j]
  bf16x8 qf0, qf1;
  {
    const u16* qrow = q + base + (size_t)(qt * 64 + wave * 16 + cl) * ND;
    qf0 = *reinterpret_cast<const bf16x8*>(qrow + g * 8);
    qf1 = *reinterpret_cast<const bf16x8*>(qrow + 32 + g * 8);
  }

  f32x4 o[4] = {};
  float mrun = -1e30f;   // per-lane: softmax row q = cl
  float lrun = 0.f;

  const u16* kg = k + base;
  const u16* vg = v + base;
  const int c0 = wave * 2;
  const int ntiles = qt + 1;

  for (int kt = 0; kt < ntiles; ++kt){
    __syncthreads();   // all waves done reading previous tile
    gld_lds16(&Ks[(c0    ) * 512], kg + (c0    ) * 512 + lane * 8);
    gld_lds16(&Ks[(c0 + 1) * 512], kg + (c0 + 1) * 512 + lane * 8);
    gld_lds16(&Vt[(c0    ) * 512], vg + (c0    ) * 512 + lane * 8);
    gld_lds16(&Vt[(c0 + 1) * 512], vg + (c0 + 1) * 512 + lane * 8);
    kg += 4096; vg += 4096;
    __syncthreads();   // staging visible (barrier drains vmcnt)

    // ---- S^T = K Q^T : s[nf] holds S^T[k = nf*16 + g*4 + r][q = cl] ----
    f32x4 s[4];
#pragma unroll
    for (int nf = 0; nf < 4; nf++){
      const int kj = nf * 16 + cl;
      const u16* krow = &Ks[kj * 64];
      const bf16x8 kf0 = *reinterpret_cast<const bf16x8*>(&krow[((0 + g) ^ (kj & 7)) * 8]);
      const bf16x8 kf1 = *reinterpret_cast<const bf16x8*>(&krow[((4 + g) ^ (kj & 7)) * 8]);
      f32x4 a = {};
      a = __builtin_amdgcn_mfma_f32_16x16x32_bf16(kf0, qf0, a, 0, 0, 0);
      a = __builtin_amdgcn_mfma_f32_16x16x32_bf16(kf1, qf1, a, 0, 0, 0);
      s[nf] = a;
    }

    // ---- causal mask (diagonal tile only; tiles are 64-aligned) ----
    if (kt == qt){
      const int qrl = wave * 16 + cl;
#pragma unroll
      for (int nf = 0; nf < 4; nf++)
#pragma unroll
        for (int r = 0; r < 4; r++)
          if (nf * 16 + g * 4 + r > qrl) s[nf][r] = -3e38f;
    }

    // ---- in-register online softmax (log2 domain) ----
    float rmax = -3e38f;
#pragma unroll
    for (int nf = 0; nf < 4; nf++)
#pragma unroll
      for (int r = 0; r < 4; r++) rmax = fmaxf(rmax, s[nf][r]);
    rmax = fmaxf(rmax, __shfl_xor(rmax, 16));
    rmax = fmaxf(rmax, __shfl_xor(rmax, 32));
    const float mnew = fmaxf(mrun, rmax);
    const float alpha = exp2f(mrun - mnew);
    mrun = mnew;
    float rs = 0.f;
#pragma unroll
    for (int nf = 0; nf < 4; nf++)
#pragma unroll
      for (int r = 0; r < 4; r++){
        s[nf][r] = exp2f(s[nf][r] - mnew);
        rs += s[nf][r];
      }
    rs += __shfl_xor(rs, 16);
    rs += __shfl_xor(rs, 32);
    lrun = lrun * alpha + rs;

    // alpha for o-rows (o row q' = g*4+r; alpha lives in lanes cl==q')
    const float a0 = __shfl(alpha, g * 4 + 0);
    const float a1 = __shfl(alpha, g * 4 + 1);
    const float a2 = __shfl(alpha, g * 4 + 2);
    const float a3 = __shfl(alpha, g * 4 + 3);
#pragma unroll
    for (int fo = 0; fo < 4; fo++){
      o[fo][0] *= a0; o[fo][1] *= a1; o[fo][2] *= a2; o[fo][3] *= a3;
    }

    // ---- P -> bf16 A-frags (k = g*4 + j matches S^T C-layout rows) ----
    u32 pk[4][2];
#pragma unroll
    for (int nf = 0; nf < 4; nf++){
      asm("v_cvt_pk_bf16_f32 %0, %1, %2" : "=v"(pk[nf][0]) : "v"(s[nf][0]), "v"(s[nf][1]));
      asm("v_cvt_pk_bf16_f32 %0, %1, %2" : "=v"(pk[nf][1]) : "v"(s[nf][2]), "v"(s[nf][3]));
    }

    // ---- O += P V  (4 k-blocks of 16 via mfma_16x16x16) ----
#pragma unroll
    for (int nf = 0; nf < 4; nf++){
      union { u32 u[2]; bf16x4 v; } pa;
      pa.u[0] = pk[nf][0]; pa.u[1] = pk[nf][1];
#pragma unroll
      for (int fo = 0; fo < 4; fo++){
        const int d = fo * 16 + cl;
        const bf16x4 vf = *reinterpret_cast<const bf16x4*>(
            &Vt[d * 64 + (((nf * 4 + g) ^ (d & 7)) << 2)]);
        o[fo] = mfma16(pa.v, vf, o[fo]);
      }
    }
  }

  // ---- epilogue: O/l -> attn_out [B,T,C] bf16 ----
  float linv[4];
#pragma unroll
  for (int r = 0; r < 4; r++) linv[r] = 1.0f / __shfl(lrun, g * 4 + r);
  const int b = bh >> 4, h = bh & 15;
#pragma unroll
  for (int fo = 0; fo < 4; fo++){
#pragma unroll
    for (int r = 0; r < 4; r++){
      const int t = qt * 64 + wave * 16 + g * 4 + r;
      const int c = h * 64 + fo * 16 + cl;
      ao[((size_t)b * NT + t) * NC + c] = f2bf(o[fo][r] * linv[r]);
    }
  }
}

extern "C" void kernel_launch(void* const* d_in, const int* in_sizes, int n_in,
                              void* d_out, int out_size, void* d_ws, size_t ws_size,
                              hipStream_t stream){
  const float* x      = (const float*)d_in[0];
  const float* w_qkv  = (const float*)d_in[1];
  const float* b_qkv  = (const float*)d_in[2];
  const float* w_proj = (const float*)d_in[3];
  const float* b_proj = (const float*)d_in[4];
  float* out = (float*)d_out;

  u16* ws = (u16*)d_ws;
  u16* xb     = ws;                 //  [B,T,C] bf16
  u16* qb     = ws + 8388608;       //  [B,H,T,D] standard
  u16* kb     = ws + 16777216;      //  [B,H] x tiles, swizzled
  u16* vb     = ws + 25165824;      //  [B,H] x tiles, transposed+swizzled
  u16* aob    = ws + 33554432;      //  [B,T,C]
  u16* wqkvT  = ws + 41943040;      //  [3C,C]
  u16* wprojT = ws + 45088768;      //  [C,C]

  k_cast<<<8388608 / 1024, 256, 0, stream>>>(x, xb);
  k_transpose_cast<<<dim3(N3C / 32, NC / 32), dim3(32, 8), 0, stream>>>(w_qkv, wqkvT, NC, N3C);
  k_transpose_cast<<<dim3(NC / 32, NC / 32), dim3(32, 8), 0, stream>>>(w_proj, wprojT, NC, NC);
  k_gemm_qkv<<<dim3(N3C / 128, NM / 128), 256, 0, stream>>>(xb, wqkvT, b_qkv, qb, kb, vb);
  k_flash<<<dim3(NT / 64, NB * NH), 256, 0, stream>>>(qb, kb, vb, aob);
  k_gemm_proj<<<dim3(NC / 128, NM / 128), 256, 0, stream>>>(aob, wprojT, b_proj, out);
}

// Round 8
// 228.677 us; speedup vs baseline: 1.6027x; 1.2818x over previous
//
#include <hip/hip_runtime.h>
#include <cstdint>

typedef unsigned short u16;
typedef uint32_t u32;
typedef __attribute__((ext_vector_type(8))) short bf16x8;
typedef __attribute__((ext_vector_type(4))) short bf16x4;
typedef __attribute__((ext_vector_type(4))) float f32x4;

#define NB 4
#define NT 2048
#define NC 1024
#define NH 16
#define ND 64
#define NM (NB*NT)      // 8192
#define N3C (3*NC)      // 3072
#define NQT (NT/64)     // 32 q-tiles per (b,h)

// Q scale: 1/sqrt(64) * log2(e)  (softmax runs in log2 domain -> exp2)
#define QSCALE 0.18033688011112042f

static __device__ __forceinline__ u16 f2bf(float f){
  union { float f; uint32_t u; } v; v.f = f;
  return (u16)((v.u + 0x7fffu + ((v.u >> 16) & 1u)) >> 16);
}

// async 16B global->LDS (LDS dest is wave-uniform base + lane*16)
static __device__ __forceinline__ void gld_lds16(void* lds, const void* g){
  auto lp = reinterpret_cast<__attribute__((address_space(3))) uint32_t*>(
      reinterpret_cast<uintptr_t>(lds));
  auto gp = reinterpret_cast<__attribute__((address_space(1))) uint32_t*>(
      reinterpret_cast<uintptr_t>(g));
  __builtin_amdgcn_global_load_lds(gp, lp, 16, 0, 0);
}

static __device__ __forceinline__ f32x4 mfma16(bf16x4 a, bf16x4 b, f32x4 c){
#if __has_builtin(__builtin_amdgcn_mfma_f32_16x16x16bf16_1k)
  return __builtin_amdgcn_mfma_f32_16x16x16bf16_1k(a, b, c, 0, 0, 0);
#else
  asm("v_mfma_f32_16x16x16_bf16 %0, %1, %2, %0" : "+v"(c) : "v"(a), "v"(b));
  return c;
#endif
}

// ---------------- elementwise cast fp32 -> bf16 ----------------
__global__ __launch_bounds__(256) void k_cast(const float* __restrict__ in,
                                              u16* __restrict__ out){
  const int i = (blockIdx.x * 256 + threadIdx.x) * 4;
  const float4 vv = *reinterpret_cast<const float4*>(in + i);
  union { u16 s[4]; uint64_t u; } pk;
  pk.s[0] = f2bf(vv.x); pk.s[1] = f2bf(vv.y);
  pk.s[2] = f2bf(vv.z); pk.s[3] = f2bf(vv.w);
  *reinterpret_cast<uint64_t*>(out + i) = pk.u;
}

// ---------------- tiled transpose + cast: in[R][Cc] fp32 -> out[Cc][R] bf16 ----------------
__global__ __launch_bounds__(256) void k_transpose_cast(const float* __restrict__ in,
                                                        u16* __restrict__ out,
                                                        int R, int Cc){
  __shared__ float tile[32][33];
  const int bx = blockIdx.x * 32, by = blockIdx.y * 32;
  const int tx = threadIdx.x, ty = threadIdx.y;
#pragma unroll
  for (int i = 0; i < 32; i += 8)
    tile[ty + i][tx] = in[(size_t)(by + ty + i) * Cc + bx + tx];
  __syncthreads();
#pragma unroll
  for (int i = 0; i < 32; i += 8)
    out[(size_t)(bx + ty + i) * R + by + tx] = f2bf(tile[tx][ty + i]);
}

// ---------------- shared GEMM main loop: C[128x128] tile, A[M][K] * Bt[N][K]^T ----------------
static __device__ __forceinline__ void gemm_mainloop(
    const u16* __restrict__ A, const u16* __restrict__ Bt, int K,
    int m0, int n0, u16* As, u16* Bs, f32x4 acc[4][4])
{
  const int tid = threadIdx.x;
  const int wave = tid >> 6, lane = tid & 63;
  const int wm = wave >> 1, wn = wave & 1;
  const int o0 = tid * 8, o1 = o0 + 2048;           // elem offsets in the 128x32 tile
  const u16* Ag0 = A  + (size_t)(m0 + (o0 >> 5)) * K + (o0 & 31);
  const u16* Ag1 = A  + (size_t)(m0 + (o1 >> 5)) * K + (o1 & 31);
  const u16* Bg0 = Bt + (size_t)(n0 + (o0 >> 5)) * K + (o0 & 31);
  const u16* Bg1 = Bt + (size_t)(n0 + (o1 >> 5)) * K + (o1 & 31);
  u16* AsW = As + wave * 512;   // wave-uniform LDS base (1024 B per wave)
  u16* BsW = Bs + wave * 512;
  const int kb = (lane >> 4) * 8, rl = lane & 15;

  for (int kt = 0; kt < K; kt += 32){
    gld_lds16(AsW,        Ag0 + kt);
    gld_lds16(AsW + 2048, Ag1 + kt);
    gld_lds16(BsW,        Bg0 + kt);
    gld_lds16(BsW + 2048, Bg1 + kt);
    __syncthreads();
    bf16x8 af[4], bfr[4];
#pragma unroll
    for (int i = 0; i < 4; i++){
      af[i]  = *reinterpret_cast<const bf16x8*>(&As[(wm * 64 + i * 16 + rl) * 32 + kb]);
      bfr[i] = *reinterpret_cast<const bf16x8*>(&Bs[(wn * 64 + i * 16 + rl) * 32 + kb]);
    }
#pragma unroll
    for (int i = 0; i < 4; i++)
#pragma unroll
      for (int j = 0; j < 4; j++)
        acc[i][j] = __builtin_amdgcn_mfma_f32_16x16x32_bf16(af[i], bfr[j], acc[i][j], 0, 0, 0);
    __syncthreads();
  }
}

// ---------------- GEMM 1: x @ w_qkv + b_qkv -> Q (scaled), K (swizzled), V (transposed+swizzled) ----------------
// Q: [b,h,t,d] standard, values * QSCALE
// K: per (b,h): tile kt (4096 elems): (t&63)*64 + (d ^ ((t&7)<<3))
// V: per (b,h): tile kt (4096 elems): d*64 + (((t>>2)&15 ^ (d&7))<<2) + (t&3)   [transposed]
__global__ __launch_bounds__(256) void k_gemm_qkv(
    const u16* __restrict__ A, const u16* __restrict__ Bt,
    const float* __restrict__ bias,
    u16* __restrict__ qo, u16* __restrict__ ko, u16* __restrict__ vo)
{
  __shared__ u16 As[128 * 32], Bs[128 * 32];
  f32x4 acc[4][4] = {};
  const int m0 = blockIdx.y * 128, n0 = blockIdx.x * 128;
  gemm_mainloop(A, Bt, NC, m0, n0, As, Bs, acc);

  const int tid = threadIdx.x;
  const int wave = tid >> 6, lane = tid & 63;
  const int wm = wave >> 1, wn = wave & 1;
  const int rl = lane & 15, rg = lane >> 4;
  const int which = n0 >> 10;   // uniform per block: 0=Q 1=K 2=V
  if (which == 2){
    // V: pack 4 consecutive t (r=0..3, t&3=r) into one 8B store
#pragma unroll
    for (int j = 0; j < 4; j++){
      const int n = n0 + wn * 64 + j * 16 + rl;
      const int cc = n & 1023;
      const int h = cc >> 6, d = cc & 63;
      const float bb = bias[n];
#pragma unroll
      for (int i = 0; i < 4; i++){
        const int mb = m0 + wm * 64 + i * 16 + rg * 4;
        const int b = mb >> 11, t0 = mb & 2047;
        const size_t bhb = ((size_t)(b * NH + h)) * NT * ND;
        union { u16 s[4]; uint64_t u; } pk4;
#pragma unroll
        for (int r = 0; r < 4; r++) pk4.s[r] = f2bf(acc[i][j][r] + bb);
        *reinterpret_cast<uint64_t*>(
          &vo[bhb + (size_t)(t0 >> 6) * 4096 + d * 64 + ((((t0 >> 2) & 15) ^ (d & 7)) << 2)]) = pk4.u;
      }
    }
  } else {
#pragma unroll
    for (int j = 0; j < 4; j++){
      const int n = n0 + wn * 64 + j * 16 + rl;
      const int cc = n & 1023;
      const int h = cc >> 6, d = cc & 63;
      const float bb = bias[n];
#pragma unroll
      for (int i = 0; i < 4; i++){
#pragma unroll
        for (int r = 0; r < 4; r++){
          const int m = m0 + wm * 64 + i * 16 + rg * 4 + r;
          const int b = m >> 11, t = m & 2047;
          const size_t bhb = ((size_t)(b * NH + h)) * NT * ND;
          const float val = acc[i][j][r] + bb;
          if (which == 0){
            qo[bhb + (size_t)t * ND + d] = f2bf(val * QSCALE);
          } else {
            ko[bhb + (size_t)(t >> 6) * 4096 + (t & 63) * 64 + (d ^ ((t & 7) << 3))] = f2bf(val);
          }
        }
      }
    }
  }
}

// ---------------- GEMM 2: attn_out @ w_proj + b_proj -> fp32 out ----------------
__global__ __launch_bounds__(256) void k_gemm_proj(
    const u16* __restrict__ A, const u16* __restrict__ Bt,
    const float* __restrict__ bias, float* __restrict__ out)
{
  __shared__ u16 As[128 * 32], Bs[128 * 32];
  f32x4 acc[4][4] = {};
  const int m0 = blockIdx.y * 128, n0 = blockIdx.x * 128;
  gemm_mainloop(A, Bt, NC, m0, n0, As, Bs, acc);

  const int tid = threadIdx.x;
  const int wave = tid >> 6, lane = tid & 63;
  const int wm = wave >> 1, wn = wave & 1;
  const int rl = lane & 15, rg = lane >> 4;
#pragma unroll
  for (int i = 0; i < 4; i++){
#pragma unroll
    for (int r = 0; r < 4; r++){
      const int m = m0 + wm * 64 + i * 16 + rg * 4 + r;
#pragma unroll
      for (int j = 0; j < 4; j++){
        const int n = n0 + wn * 64 + j * 16 + rl;
        out[(size_t)m * NC + n] = acc[i][j][r] + bias[n];
      }
    }
  }
}

// ---------------- flash attention for ONE 64-row q-tile, double-buffered staging ----------------
// Raw s_barrier + counted vmcnt: stage(t+1) loads stay in flight across the barrier (T3-min/T4).
static __device__ __forceinline__ void flash_one(
    int qt, const u16* __restrict__ q, const u16* __restrict__ kb,
    const u16* __restrict__ vb, u16* __restrict__ ao, int bh,
    u16 (*Ks)[4096], u16 (*Vt)[4096])
{
  const int tid = threadIdx.x, wave = tid >> 6, lane = tid & 63;
  const int cl = lane & 15, g = lane >> 4;
  const int c0 = wave * 2;
  const size_t base = (size_t)bh * NT * ND;
  const u16* kg0 = kb + base;
  const u16* vg0 = vb + base;

  // Q frag: lane holds Q[q=cl][d=g*8+j]; force-materialize so staging vmcnt stays pure
  bf16x8 qf0, qf1;
  {
    const u16* qrow = q + base + (size_t)(qt * 64 + wave * 16 + cl) * ND;
    qf0 = *reinterpret_cast<const bf16x8*>(qrow + g * 8);
    qf1 = *reinterpret_cast<const bf16x8*>(qrow + 32 + g * 8);
  }
  asm volatile("" : "+v"(qf0), "+v"(qf1));

  f32x4 o[4] = {};
  float mrun = -1e30f, lrun = 0.f;
  const int n = qt + 1;

  // prologue: stage tile 0 -> buf 0 (4 gld_lds16 per wave)
  gld_lds16(&Ks[0][(c0    ) * 512], kg0 + (c0    ) * 512 + lane * 8);
  gld_lds16(&Ks[0][(c0 + 1) * 512], kg0 + (c0 + 1) * 512 + lane * 8);
  gld_lds16(&Vt[0][(c0    ) * 512], vg0 + (c0    ) * 512 + lane * 8);
  gld_lds16(&Vt[0][(c0 + 1) * 512], vg0 + (c0 + 1) * 512 + lane * 8);

  for (int t = 0; t < n; ++t){
    const int cur = t & 1, nxt = cur ^ 1;
    if (t + 1 < n){
      const u16* kg = kg0 + (size_t)(t + 1) * 4096;
      const u16* vg = vg0 + (size_t)(t + 1) * 4096;
      gld_lds16(&Ks[nxt][(c0    ) * 512], kg + (c0    ) * 512 + lane * 8);
      gld_lds16(&Ks[nxt][(c0 + 1) * 512], kg + (c0 + 1) * 512 + lane * 8);
      gld_lds16(&Vt[nxt][(c0    ) * 512], vg + (c0    ) * 512 + lane * 8);
      gld_lds16(&Vt[nxt][(c0 + 1) * 512], vg + (c0 + 1) * 512 + lane * 8);
      asm volatile("s_waitcnt vmcnt(4)" ::: "memory");   // own tile-t loads done; t+1 in flight
    } else {
      asm volatile("s_waitcnt vmcnt(0)" ::: "memory");
    }
    __builtin_amdgcn_sched_barrier(0);
    __builtin_amdgcn_s_barrier();    // raw: no implicit vmcnt(0) drain

    // ---- S^T = K Q^T : s[nf] holds S^T[k = nf*16 + g*4 + r][q = cl] ----
    const u16* KsC = Ks[cur];
    const u16* VtC = Vt[cur];
    f32x4 s[4];
    __builtin_amdgcn_s_setprio(1);
#pragma unroll
    for (int nf = 0; nf < 4; nf++){
      const int kj = nf * 16 + cl;
      const u16* krow = &KsC[kj * 64];
      const bf16x8 kf0 = *reinterpret_cast<const bf16x8*>(&krow[((0 + g) ^ (kj & 7)) * 8]);
      const bf16x8 kf1 = *reinterpret_cast<const bf16x8*>(&krow[((4 + g) ^ (kj & 7)) * 8]);
      f32x4 a = {};
      a = __builtin_amdgcn_mfma_f32_16x16x32_bf16(kf0, qf0, a, 0, 0, 0);
      a = __builtin_amdgcn_mfma_f32_16x16x32_bf16(kf1, qf1, a, 0, 0, 0);
      s[nf] = a;
    }
    __builtin_amdgcn_s_setprio(0);

    // ---- causal mask (diagonal tile only; tiles are 64-aligned) ----
    if (t == qt){
      const int qrl = wave * 16 + cl;
#pragma unroll
      for (int nf = 0; nf < 4; nf++)
#pragma unroll
        for (int r = 0; r < 4; r++)
          if (nf * 16 + g * 4 + r > qrl) s[nf][r] = -3e38f;
    }

    // ---- in-register online softmax (log2 domain) ----
    float rmax = -3e38f;
#pragma unroll
    for (int nf = 0; nf < 4; nf++)
#pragma unroll
      for (int r = 0; r < 4; r++) rmax = fmaxf(rmax, s[nf][r]);
    rmax = fmaxf(rmax, __shfl_xor(rmax, 16));
    rmax = fmaxf(rmax, __shfl_xor(rmax, 32));
    const float mnew = fmaxf(mrun, rmax);
    const float alpha = exp2f(mrun - mnew);
    mrun = mnew;
    float rs = 0.f;
#pragma unroll
    for (int nf = 0; nf < 4; nf++)
#pragma unroll
      for (int r = 0; r < 4; r++){
        s[nf][r] = exp2f(s[nf][r] - mnew);
        rs += s[nf][r];
      }
    rs += __shfl_xor(rs, 16);
    rs += __shfl_xor(rs, 32);
    lrun = lrun * alpha + rs;

    // alpha for o-rows (o row q' = g*4+r; alpha lives in lanes cl==q')
    const float a0 = __shfl(alpha, g * 4 + 0);
    const float a1 = __shfl(alpha, g * 4 + 1);
    const float a2 = __shfl(alpha, g * 4 + 2);
    const float a3 = __shfl(alpha, g * 4 + 3);
#pragma unroll
    for (int fo = 0; fo < 4; fo++){
      o[fo][0] *= a0; o[fo][1] *= a1; o[fo][2] *= a2; o[fo][3] *= a3;
    }

    // ---- P -> bf16 A-frags (k = g*4 + j matches S^T C-layout rows) ----
    u32 pk[4][2];
#pragma unroll
    for (int nf = 0; nf < 4; nf++){
      asm("v_cvt_pk_bf16_f32 %0, %1, %2" : "=v"(pk[nf][0]) : "v"(s[nf][0]), "v"(s[nf][1]));
      asm("v_cvt_pk_bf16_f32 %0, %1, %2" : "=v"(pk[nf][1]) : "v"(s[nf][2]), "v"(s[nf][3]));
    }

    // ---- O += P V  (4 k-blocks of 16 via mfma_16x16x16) ----
    __builtin_amdgcn_s_setprio(1);
#pragma unroll
    for (int nf = 0; nf < 4; nf++){
      union { u32 u[2]; bf16x4 v; } pa;
      pa.u[0] = pk[nf][0]; pa.u[1] = pk[nf][1];
#pragma unroll
      for (int fo = 0; fo < 4; fo++){
        const int d = fo * 16 + cl;
        const bf16x4 vf = *reinterpret_cast<const bf16x4*>(
            &VtC[d * 64 + (((nf * 4 + g) ^ (d & 7)) << 2)]);
        o[fo] = mfma16(pa.v, vf, o[fo]);
      }
    }
    __builtin_amdgcn_s_setprio(0);

    asm volatile("s_waitcnt lgkmcnt(0)" ::: "memory");   // all LDS reads of buf[cur] sampled
    __builtin_amdgcn_sched_barrier(0);
    __builtin_amdgcn_s_barrier();    // release buf[cur] for stage(t+2)
  }

  // ---- epilogue: O/l -> attn_out [B,T,C] bf16 ----
  float linv[4];
#pragma unroll
  for (int r = 0; r < 4; r++) linv[r] = 1.0f / __shfl(lrun, g * 4 + r);
  const int b = bh >> 4, h = bh & 15;
#pragma unroll
  for (int fo = 0; fo < 4; fo++){
#pragma unroll
    for (int r = 0; r < 4; r++){
      const int t = qt * 64 + wave * 16 + g * 4 + r;
      const int c = h * 64 + fo * 16 + cl;
      ao[((size_t)b * NT + t) * NC + c] = f2bf(o[fo][r] * linv[r]);
    }
  }
}

// ---------------- causal flash attention, work-balanced: block px does q-tiles {px, 31-px} ----------------
__global__ __launch_bounds__(256) void k_flash(
    const u16* __restrict__ q, const u16* __restrict__ k,
    const u16* __restrict__ v, u16* __restrict__ ao)
{
  __shared__ u16 Ks[2][4096];   // [buf][kj*64 + swizzled-d], 16B-chunk swizzle: chunk' = chunk ^ (kj&7)
  __shared__ u16 Vt[2][4096];   // [buf][d*64 + swizzled-kj], 8B-chunk swizzle
  const int px = blockIdx.x, bh = blockIdx.y;
  flash_one(px,           q, k, v, ao, bh, Ks, Vt);
  __builtin_amdgcn_s_barrier();                    // (defensive) all waves done with bufs
  flash_one(NQT - 1 - px, q, k, v, ao, bh, Ks, Vt);
}

extern "C" void kernel_launch(void* const* d_in, const int* in_sizes, int n_in,
                              void* d_out, int out_size, void* d_ws, size_t ws_size,
                              hipStream_t stream){
  const float* x      = (const float*)d_in[0];
  const float* w_qkv  = (const float*)d_in[1];
  const float* b_qkv  = (const float*)d_in[2];
  const float* w_proj = (const float*)d_in[3];
  const float* b_proj = (const float*)d_in[4];
  float* out = (float*)d_out;

  u16* ws = (u16*)d_ws;
  u16* xb     = ws;                 //  [B,T,C] bf16
  u16* qb     = ws + 8388608;       //  [B,H,T,D] standard
  u16* kb     = ws + 16777216;      //  [B,H] x tiles, swizzled
  u16* vb     = ws + 25165824;      //  [B,H] x tiles, transposed+swizzled
  u16* aob    = ws + 33554432;      //  [B,T,C]
  u16* wqkvT  = ws + 41943040;      //  [3C,C]
  u16* wprojT = ws + 45088768;      //  [C,C]

  k_cast<<<8388608 / 1024, 256, 0, stream>>>(x, xb);
  k_transpose_cast<<<dim3(N3C / 32, NC / 32), dim3(32, 8), 0, stream>>>(w_qkv, wqkvT, NC, N3C);
  k_transpose_cast<<<dim3(NC / 32, NC / 32), dim3(32, 8), 0, stream>>>(w_proj, wprojT, NC, NC);
  k_gemm_qkv<<<dim3(N3C / 128, NM / 128), 256, 0, stream>>>(xb, wqkvT, b_qkv, qb, kb, vb);
  k_flash<<<dim3(NQT / 2, NB * NH), 256, 0, stream>>>(qb, kb, vb, aob);
  k_gemm_proj<<<dim3(NC / 128, NM / 128), 256, 0, stream>>>(aob, wprojT, b_proj, out);
}

// Round 9
// 223.241 us; speedup vs baseline: 1.6417x; 1.0243x over previous
//
#include <hip/hip_runtime.h>
#include <cstdint>

typedef unsigned short u16;
typedef uint32_t u32;
typedef __attribute__((ext_vector_type(8))) short bf16x8;
typedef __attribute__((ext_vector_type(4))) short bf16x4;
typedef __attribute__((ext_vector_type(4))) float f32x4;

#define NB 4
#define NT 2048
#define NC 1024
#define NH 16
#define ND 64
#define NM (NB*NT)      // 8192
#define N3C (3*NC)      // 3072
#define NQT (NT/64)     // 32 q-tiles per (b,h)

// Q scale: 1/sqrt(64) * log2(e)  (softmax runs in log2 domain -> exp2)
#define QSCALE 0.18033688011112042f

static __device__ __forceinline__ u16 f2bf(float f){
  union { float f; uint32_t u; } v; v.f = f;
  return (u16)((v.u + 0x7fffu + ((v.u >> 16) & 1u)) >> 16);
}

// async 16B global->LDS (LDS dest is wave-uniform base + lane*16)
static __device__ __forceinline__ void gld_lds16(void* lds, const void* g){
  auto lp = reinterpret_cast<__attribute__((address_space(3))) uint32_t*>(
      reinterpret_cast<uintptr_t>(lds));
  auto gp = reinterpret_cast<__attribute__((address_space(1))) uint32_t*>(
      reinterpret_cast<uintptr_t>(g));
  __builtin_amdgcn_global_load_lds(gp, lp, 16, 0, 0);
}

static __device__ __forceinline__ f32x4 mfma16(bf16x4 a, bf16x4 b, f32x4 c){
#if __has_builtin(__builtin_amdgcn_mfma_f32_16x16x16bf16_1k)
  return __builtin_amdgcn_mfma_f32_16x16x16bf16_1k(a, b, c, 0, 0, 0);
#else
  asm("v_mfma_f32_16x16x16_bf16 %0, %1, %2, %0" : "+v"(c) : "v"(a), "v"(b));
  return c;
#endif
}

// ---------------- elementwise cast fp32 -> bf16 ----------------
__global__ __launch_bounds__(256) void k_cast(const float* __restrict__ in,
                                              u16* __restrict__ out){
  const int i = (blockIdx.x * 256 + threadIdx.x) * 4;
  const float4 vv = *reinterpret_cast<const float4*>(in + i);
  union { u16 s[4]; uint64_t u; } pk;
  pk.s[0] = f2bf(vv.x); pk.s[1] = f2bf(vv.y);
  pk.s[2] = f2bf(vv.z); pk.s[3] = f2bf(vv.w);
  *reinterpret_cast<uint64_t*>(out + i) = pk.u;
}

// ---------------- tiled transpose + cast: in[R][Cc] fp32 -> out[Cc][R] bf16 ----------------
__global__ __launch_bounds__(256) void k_transpose_cast(const float* __restrict__ in,
                                                        u16* __restrict__ out,
                                                        int R, int Cc){
  __shared__ float tile[32][33];
  const int bx = blockIdx.x * 32, by = blockIdx.y * 32;
  const int tx = threadIdx.x, ty = threadIdx.y;
#pragma unroll
  for (int i = 0; i < 32; i += 8)
    tile[ty + i][tx] = in[(size_t)(by + ty + i) * Cc + bx + tx];
  __syncthreads();
#pragma unroll
  for (int i = 0; i < 32; i += 8)
    out[(size_t)(bx + ty + i) * R + by + tx] = f2bf(tile[tx][ty + i]);
}

// ---------------- shared GEMM main loop: C[128x128] tile, A[M][K] * Bt[N][K]^T ----------------
static __device__ __forceinline__ void gemm_mainloop(
    const u16* __restrict__ A, const u16* __restrict__ Bt, int K,
    int m0, int n0, u16* As, u16* Bs, f32x4 acc[4][4])
{
  const int tid = threadIdx.x;
  const int wave = tid >> 6, lane = tid & 63;
  const int wm = wave >> 1, wn = wave & 1;
  const int o0 = tid * 8, o1 = o0 + 2048;           // elem offsets in the 128x32 tile
  const u16* Ag0 = A  + (size_t)(m0 + (o0 >> 5)) * K + (o0 & 31);
  const u16* Ag1 = A  + (size_t)(m0 + (o1 >> 5)) * K + (o1 & 31);
  const u16* Bg0 = Bt + (size_t)(n0 + (o0 >> 5)) * K + (o0 & 31);
  const u16* Bg1 = Bt + (size_t)(n0 + (o1 >> 5)) * K + (o1 & 31);
  u16* AsW = As + wave * 512;   // wave-uniform LDS base (1024 B per wave)
  u16* BsW = Bs + wave * 512;
  const int kb = (lane >> 4) * 8, rl = lane & 15;

  for (int kt = 0; kt < K; kt += 32){
    gld_lds16(AsW,        Ag0 + kt);
    gld_lds16(AsW + 2048, Ag1 + kt);
    gld_lds16(BsW,        Bg0 + kt);
    gld_lds16(BsW + 2048, Bg1 + kt);
    __syncthreads();
    bf16x8 af[4], bfr[4];
#pragma unroll
    for (int i = 0; i < 4; i++){
      af[i]  = *reinterpret_cast<const bf16x8*>(&As[(wm * 64 + i * 16 + rl) * 32 + kb]);
      bfr[i] = *reinterpret_cast<const bf16x8*>(&Bs[(wn * 64 + i * 16 + rl) * 32 + kb]);
    }
#pragma unroll
    for (int i = 0; i < 4; i++)
#pragma unroll
      for (int j = 0; j < 4; j++)
        acc[i][j] = __builtin_amdgcn_mfma_f32_16x16x32_bf16(af[i], bfr[j], acc[i][j], 0, 0, 0);
    __syncthreads();
  }
}

// ---------------- GEMM 1: x @ w_qkv + b_qkv -> Q (scaled), K (swizzled), V (transposed+swizzled) ----------------
// Q: [b,h,t,d] standard, values * QSCALE
// K: per (b,h): tile kt (4096 elems): (t&63)*64 + (d ^ ((t&7)<<3))
// V: per (b,h): tile kt (4096 elems): d*64 + (((t>>2)&15 ^ (d&7))<<2) + (t&3)   [transposed]
__global__ __launch_bounds__(256) void k_gemm_qkv(
    const u16* __restrict__ A, const u16* __restrict__ Bt,
    const float* __restrict__ bias,
    u16* __restrict__ qo, u16* __restrict__ ko, u16* __restrict__ vo)
{
  __shared__ u16 As[128 * 32], Bs[128 * 32];
  f32x4 acc[4][4] = {};
  const int m0 = blockIdx.y * 128, n0 = blockIdx.x * 128;
  gemm_mainloop(A, Bt, NC, m0, n0, As, Bs, acc);

  const int tid = threadIdx.x;
  const int wave = tid >> 6, lane = tid & 63;
  const int wm = wave >> 1, wn = wave & 1;
  const int rl = lane & 15, rg = lane >> 4;
  const int which = n0 >> 10;   // uniform per block: 0=Q 1=K 2=V
  if (which == 2){
    // V: pack 4 consecutive t (r=0..3, t&3=r) into one 8B store
#pragma unroll
    for (int j = 0; j < 4; j++){
      const int n = n0 + wn * 64 + j * 16 + rl;
      const int cc = n & 1023;
      const int h = cc >> 6, d = cc & 63;
      const float bb = bias[n];
#pragma unroll
      for (int i = 0; i < 4; i++){
        const int mb = m0 + wm * 64 + i * 16 + rg * 4;
        const int b = mb >> 11, t0 = mb & 2047;
        const size_t bhb = ((size_t)(b * NH + h)) * NT * ND;
        union { u16 s[4]; uint64_t u; } pk4;
#pragma unroll
        for (int r = 0; r < 4; r++) pk4.s[r] = f2bf(acc[i][j][r] + bb);
        *reinterpret_cast<uint64_t*>(
          &vo[bhb + (size_t)(t0 >> 6) * 4096 + d * 64 + ((((t0 >> 2) & 15) ^ (d & 7)) << 2)]) = pk4.u;
      }
    }
  } else {
#pragma unroll
    for (int j = 0; j < 4; j++){
      const int n = n0 + wn * 64 + j * 16 + rl;
      const int cc = n & 1023;
      const int h = cc >> 6, d = cc & 63;
      const float bb = bias[n];
#pragma unroll
      for (int i = 0; i < 4; i++){
#pragma unroll
        for (int r = 0; r < 4; r++){
          const int m = m0 + wm * 64 + i * 16 + rg * 4 + r;
          const int b = m >> 11, t = m & 2047;
          const size_t bhb = ((size_t)(b * NH + h)) * NT * ND;
          const float val = acc[i][j][r] + bb;
          if (which == 0){
            qo[bhb + (size_t)t * ND + d] = f2bf(val * QSCALE);
          } else {
            ko[bhb + (size_t)(t >> 6) * 4096 + (t & 63) * 64 + (d ^ ((t & 7) << 3))] = f2bf(val);
          }
        }
      }
    }
  }
}

// ---------------- GEMM 2: attn_out @ w_proj + b_proj -> fp32 out ----------------
__global__ __launch_bounds__(256) void k_gemm_proj(
    const u16* __restrict__ A, const u16* __restrict__ Bt,
    const float* __restrict__ bias, float* __restrict__ out)
{
  __shared__ u16 As[128 * 32], Bs[128 * 32];
  f32x4 acc[4][4] = {};
  const int m0 = blockIdx.y * 128, n0 = blockIdx.x * 128;
  gemm_mainloop(A, Bt, NC, m0, n0, As, Bs, acc);

  const int tid = threadIdx.x;
  const int wave = tid >> 6, lane = tid & 63;
  const int wm = wave >> 1, wn = wave & 1;
  const int rl = lane & 15, rg = lane >> 4;
#pragma unroll
  for (int i = 0; i < 4; i++){
#pragma unroll
    for (int r = 0; r < 4; r++){
      const int m = m0 + wm * 64 + i * 16 + rg * 4 + r;
#pragma unroll
      for (int j = 0; j < 4; j++){
        const int n = n0 + wn * 64 + j * 16 + rl;
        out[(size_t)m * NC + n] = acc[i][j][r] + bias[n];
      }
    }
  }
}

// ---------------- flash helpers ----------------
// S^T = K Q^T : s[nf] holds S^T[k = nf*16 + g*4 + r][q = cl]
static __device__ __forceinline__ void qkt(const u16* __restrict__ KsC,
                                           bf16x8 qf0, bf16x8 qf1,
                                           int cl, int g, f32x4 s[4])
{
  __builtin_amdgcn_s_setprio(1);
#pragma unroll
  for (int nf = 0; nf < 4; nf++){
    const int kj = nf * 16 + cl;
    const u16* krow = &KsC[kj * 64];
    const bf16x8 kf0 = *reinterpret_cast<const bf16x8*>(&krow[((0 + g) ^ (kj & 7)) * 8]);
    const bf16x8 kf1 = *reinterpret_cast<const bf16x8*>(&krow[((4 + g) ^ (kj & 7)) * 8]);
    f32x4 a = {};
    a = __builtin_amdgcn_mfma_f32_16x16x32_bf16(kf0, qf0, a, 0, 0, 0);
    a = __builtin_amdgcn_mfma_f32_16x16x32_bf16(kf1, qf1, a, 0, 0, 0);
    s[nf] = a;
  }
  __builtin_amdgcn_s_setprio(0);
}

static __device__ __forceinline__ void maskdiag(f32x4 s[4], int wave, int cl, int g){
  const int qrl = wave * 16 + cl;
#pragma unroll
  for (int nf = 0; nf < 4; nf++)
#pragma unroll
    for (int r = 0; r < 4; r++)
      if (nf * 16 + g * 4 + r > qrl) s[nf][r] = -3e38f;
}

// online softmax (log2 domain, defer-max THR=8) + PV accumulate
static __device__ __forceinline__ void sm_pv(
    f32x4 s[4], f32x4 o[4], float& mrun, float& lrun,
    const u16* __restrict__ VtC, int cl, int g)
{
  float rmax = -3e38f;
#pragma unroll
  for (int nf = 0; nf < 4; nf++)
#pragma unroll
    for (int r = 0; r < 4; r++) rmax = fmaxf(rmax, s[nf][r]);
  rmax = fmaxf(rmax, __shfl_xor(rmax, 16));
  rmax = fmaxf(rmax, __shfl_xor(rmax, 32));
  // defer-max: only rescale when the row max grew by >8 (P bounded by 2^8)
  if (!__all(rmax <= mrun + 8.0f)){
    const float mnew = fmaxf(mrun, rmax);
    const float alpha = exp2f(mrun - mnew);
    mrun = mnew;
    lrun *= alpha;
    const float a0 = __shfl(alpha, g * 4 + 0);
    const float a1 = __shfl(alpha, g * 4 + 1);
    const float a2 = __shfl(alpha, g * 4 + 2);
    const float a3 = __shfl(alpha, g * 4 + 3);
#pragma unroll
    for (int fo = 0; fo < 4; fo++){
      o[fo][0] *= a0; o[fo][1] *= a1; o[fo][2] *= a2; o[fo][3] *= a3;
    }
  }
  float rs = 0.f;
#pragma unroll
  for (int nf = 0; nf < 4; nf++)
#pragma unroll
    for (int r = 0; r < 4; r++){
      s[nf][r] = exp2f(s[nf][r] - mrun);
      rs += s[nf][r];
    }
  rs += __shfl_xor(rs, 16);
  rs += __shfl_xor(rs, 32);
  lrun += rs;

  u32 pk[4][2];
#pragma unroll
  for (int nf = 0; nf < 4; nf++){
    asm("v_cvt_pk_bf16_f32 %0, %1, %2" : "=v"(pk[nf][0]) : "v"(s[nf][0]), "v"(s[nf][1]));
    asm("v_cvt_pk_bf16_f32 %0, %1, %2" : "=v"(pk[nf][1]) : "v"(s[nf][2]), "v"(s[nf][3]));
  }
  __builtin_amdgcn_s_setprio(1);
#pragma unroll
  for (int nf = 0; nf < 4; nf++){
    union { u32 u[2]; bf16x4 v; } pa;
    pa.u[0] = pk[nf][0]; pa.u[1] = pk[nf][1];
#pragma unroll
    for (int fo = 0; fo < 4; fo++){
      const int d = fo * 16 + cl;
      const bf16x4 vf = *reinterpret_cast<const bf16x4*>(
          &VtC[d * 64 + (((nf * 4 + g) ^ (d & 7)) << 2)]);
      o[fo] = mfma16(pa.v, vf, o[fo]);
    }
  }
  __builtin_amdgcn_s_setprio(0);
}

// ---------------- causal flash attention: one KV sweep serves q-tiles {px, 31-px} ----------------
// Double-buffered staging, raw s_barrier + counted vmcnt (loads in flight across barriers).
__global__ __launch_bounds__(256) void k_flash(
    const u16* __restrict__ q, const u16* __restrict__ k,
    const u16* __restrict__ v, u16* __restrict__ ao)
{
  __shared__ u16 Ks[2][4096];   // [buf][kj*64 + swz-d], 16B-chunk swizzle: chunk' = chunk ^ (kj&7)
  __shared__ u16 Vt[2][4096];   // [buf][d*64 + swz-kj], 8B-chunk swizzle
  const int tid = threadIdx.x, wave = tid >> 6, lane = tid & 63;
  const int cl = lane & 15, g = lane >> 4;
  const int c0 = wave * 2;
  const int px = blockIdx.x, bh = blockIdx.y;
  const int qt1 = px, qt2 = NQT - 1 - px;
  const int ntot = qt2 + 1;
  const size_t base = (size_t)bh * NT * ND;
  const u16* kg0 = k + base;
  const u16* vg0 = v + base;

  // Q frags for both tiles: lane holds Q[q=cl][d=g*8+j]
  bf16x8 q1f0, q1f1, q2f0, q2f1;
  {
    const u16* qr1 = q + base + (size_t)(qt1 * 64 + wave * 16 + cl) * ND;
    q1f0 = *reinterpret_cast<const bf16x8*>(qr1 + g * 8);
    q1f1 = *reinterpret_cast<const bf16x8*>(qr1 + 32 + g * 8);
    const u16* qr2 = q + base + (size_t)(qt2 * 64 + wave * 16 + cl) * ND;
    q2f0 = *reinterpret_cast<const bf16x8*>(qr2 + g * 8);
    q2f1 = *reinterpret_cast<const bf16x8*>(qr2 + 32 + g * 8);
  }
  asm volatile("" : "+v"(q1f0), "+v"(q1f1), "+v"(q2f0), "+v"(q2f1));

  f32x4 o1[4] = {}, o2[4] = {};
  float m1 = -1e30f, l1 = 0.f, m2 = -1e30f, l2 = 0.f;

  // prologue: stage tile 0 -> buf 0 (4 gld_lds16 per wave)
  gld_lds16(&Ks[0][(c0    ) * 512], kg0 + (c0    ) * 512 + lane * 8);
  gld_lds16(&Ks[0][(c0 + 1) * 512], kg0 + (c0 + 1) * 512 + lane * 8);
  gld_lds16(&Vt[0][(c0    ) * 512], vg0 + (c0    ) * 512 + lane * 8);
  gld_lds16(&Vt[0][(c0 + 1) * 512], vg0 + (c0 + 1) * 512 + lane * 8);

  for (int t = 0; t < ntot; ++t){
    const int cur = t & 1, nxt = cur ^ 1;
    if (t + 1 < ntot){
      const u16* kg = kg0 + (size_t)(t + 1) * 4096;
      const u16* vg = vg0 + (size_t)(t + 1) * 4096;
      gld_lds16(&Ks[nxt][(c0    ) * 512], kg + (c0    ) * 512 + lane * 8);
      gld_lds16(&Ks[nxt][(c0 + 1) * 512], kg + (c0 + 1) * 512 + lane * 8);
      gld_lds16(&Vt[nxt][(c0    ) * 512], vg + (c0    ) * 512 + lane * 8);
      gld_lds16(&Vt[nxt][(c0 + 1) * 512], vg + (c0 + 1) * 512 + lane * 8);
      asm volatile("s_waitcnt vmcnt(4)" ::: "memory");   // own tile-t loads done; t+1 in flight
    } else {
      asm volatile("s_waitcnt vmcnt(0)" ::: "memory");
    }
    __builtin_amdgcn_sched_barrier(0);
    __builtin_amdgcn_s_barrier();    // raw: no implicit vmcnt(0) drain

    const u16* KsC = Ks[cur];
    const u16* VtC = Vt[cur];

    // state 2 (qt2): every tile
    {
      f32x4 s[4];
      qkt(KsC, q2f0, q2f1, cl, g, s);
      if (t == qt2) maskdiag(s, wave, cl, g);
      sm_pv(s, o2, m2, l2, VtC, cl, g);
    }
    // state 1 (qt1): tiles 0..qt1 (wave-uniform branch)
    if (t <= qt1){
      f32x4 s[4];
      qkt(KsC, q1f0, q1f1, cl, g, s);
      if (t == qt1) maskdiag(s, wave, cl, g);
      sm_pv(s, o1, m1, l1, VtC, cl, g);
    }

    asm volatile("s_waitcnt lgkmcnt(0)" ::: "memory");   // all LDS reads of buf[cur] sampled
    __builtin_amdgcn_sched_barrier(0);
    __builtin_amdgcn_s_barrier();    // release buf[cur] for stage(t+2)
  }

  // ---- epilogue: O/l for both q-tiles -> attn_out [B,T,C] bf16 ----
  float li1[4], li2[4];
#pragma unroll
  for (int r = 0; r < 4; r++){
    li1[r] = 1.0f / __shfl(l1, g * 4 + r);
    li2[r] = 1.0f / __shfl(l2, g * 4 + r);
  }
  const int b = bh >> 4, h = bh & 15;
#pragma unroll
  for (int fo = 0; fo < 4; fo++){
#pragma unroll
    for (int r = 0; r < 4; r++){
      const int c = h * 64 + fo * 16 + cl;
      const int t1 = qt1 * 64 + wave * 16 + g * 4 + r;
      ao[((size_t)b * NT + t1) * NC + c] = f2bf(o1[fo][r] * li1[r]);
      const int t2 = qt2 * 64 + wave * 16 + g * 4 + r;
      ao[((size_t)b * NT + t2) * NC + c] = f2bf(o2[fo][r] * li2[r]);
    }
  }
}

extern "C" void kernel_launch(void* const* d_in, const int* in_sizes, int n_in,
                              void* d_out, int out_size, void* d_ws, size_t ws_size,
                              hipStream_t stream){
  const float* x      = (const float*)d_in[0];
  const float* w_qkv  = (const float*)d_in[1];
  const float* b_qkv  = (const float*)d_in[2];
  const float* w_proj = (const float*)d_in[3];
  const float* b_proj = (const float*)d_in[4];
  float* out = (float*)d_out;

  u16* ws = (u16*)d_ws;
  u16* xb     = ws;                 //  [B,T,C] bf16
  u16* qb     = ws + 8388608;       //  [B,H,T,D] standard
  u16* kb     = ws + 16777216;      //  [B,H] x tiles, swizzled
  u16* vb     = ws + 25165824;      //  [B,H] x tiles, transposed+swizzled
  u16* aob    = ws + 33554432;      //  [B,T,C]
  u16* wqkvT  = ws + 41943040;      //  [3C,C]
  u16* wprojT = ws + 45088768;      //  [C,C]

  k_cast<<<8388608 / 1024, 256, 0, stream>>>(x, xb);
  k_transpose_cast<<<dim3(N3C / 32, NC / 32), dim3(32, 8), 0, stream>>>(w_qkv, wqkvT, NC, N3C);
  k_transpose_cast<<<dim3(NC / 32, NC / 32), dim3(32, 8), 0, stream>>>(w_proj, wprojT, NC, NC);
  k_gemm_qkv<<<dim3(N3C / 128, NM / 128), 256, 0, stream>>>(xb, wqkvT, b_qkv, qb, kb, vb);
  k_flash<<<dim3(NQT / 2, NB * NH), 256, 0, stream>>>(qb, kb, vb, aob);
  k_gemm_proj<<<dim3(NC / 128, NM / 128), 256, 0, stream>>>(aob, wprojT, b_proj, out);
}